// Round 10
// baseline (681.141 us; speedup 1.0000x reference)
//
#include <hip/hip_runtime.h>
#include <stdint.h>

#define SLOTS 28   // cols slots per (column, 512-row seg); P(Pois(5.1)>28)~4e-9
#define SEGS  8    // row segments of 512
#define CAPN  224  // SLOTS*SEGS
#define RPB   4    // rows per block in spmm (1 wave each)

typedef __attribute__((ext_vector_type(8))) short bf16x8;
typedef __attribute__((ext_vector_type(4))) float f32x4;
typedef __attribute__((ext_vector_type(4))) uint32_t u32x4;

typedef __attribute__((address_space(3))) uint32_t lds_u32;
typedef __attribute__((address_space(1))) const uint32_t glb_u32;

__device__ __forceinline__ unsigned short f2bf(float f) {
  union { float f; uint32_t u; } c; c.f = f;
  return (unsigned short)((c.u + 0x7fffu + ((c.u >> 16) & 1u)) >> 16);
}
__device__ __forceinline__ float bf2f(uint32_t b) {
  union { uint32_t u; float f; } c; c.u = b << 16; return c.f;
}
__device__ __forceinline__ float as_f32(uint32_t u) {
  union { uint32_t u; float f; } c; c.u = u; return c.f;
}

// ---------- init: dtype-detect only ----------
__global__ __launch_bounds__(256) void k_init(const uint32_t* __restrict__ a,
                                              int* __restrict__ flag) {
  __shared__ int sfound;
  int t = threadIdx.x;
  if (t == 0) sfound = 0;
  bool found = false;
  for (int i = t; i < 16384; i += 256) {
    uint32_t x = a[i];
    if (x == 0x00003F80u || x == 0x3F803F80u) found = true;
  }
  __syncthreads();
  if (found) sfound = 1;   // benign same-value race
  __syncthreads();
  if (t == 0) flag[0] = sfound;
}

// ---------- merged stage: coalesced ATOMIC-FREE CSR build + X conv + W^T ----
// Build A/B vs the 109us atomic version: SAME row-major float4/uint2 reads
// (1KB / 512B per wave-instruction), but each lane privately compacts the 4
// columns of its own vector load (lane l owns cols i0+4l..i0+4l+3) over a
// 512-row segment. Removes ONLY the atomics + dependent scatter chain.
// Emits the R9-proven segmented CSR (SLOTS=28 x SEGS=8, ascending j).
__global__ __launch_bounds__(256) void k_stage(const void* __restrict__ adjp,
                                               uint8_t* __restrict__ scnt,
                                               int* __restrict__ cols,
                                               const void* __restrict__ xp,
                                               ushort* __restrict__ xb,
                                               const void* w1, const void* w2,
                                               const void* w3,
                                               ushort* __restrict__ wt1,
                                               ushort* __restrict__ wt2,
                                               ushort* __restrict__ wt3,
                                               const int* __restrict__ flag) {
  __shared__ uint32_t lw[64][65];   // W-transpose tile (65: conflict-free)
  int bid = blockIdx.x;
  int tid = threadIdx.x;
  int flagv = flag[0];

  if (bid < 128) {
    // ---- CSR build: 128 blocks x 4 waves = 512 tasks ----
    int wid = tid >> 6, lane = tid & 63;
    int t = bid * 4 + wid;              // [0,512)
    int b = t >> 7;                     // batch
    int rem = t & 127;
    int g = rem >> 3;                   // colgroup [0,16) of 256 cols
    int s = rem & 7;                    // row segment [0,8) of 512 rows
    int i0 = g * 256;
    int jb = s * 512;
    int rb = (b << 12) + i0 + 4 * lane; // first owned CSR row (= adj column)
    int* c0 = cols + (size_t)rb * CAPN + s * SLOTS;
    int p0 = 0, p1 = 0, p2 = 0, p3 = 0;
    if (flagv) {
      const ushort* base = (const ushort*)adjp + ((size_t)b << 24) +
                           (size_t)jb * 4096 + i0 + 4 * lane;
      for (int blk = 0; blk < 512; blk += 16) {
        uint2 v[16];
#pragma unroll
        for (int u = 0; u < 16; u++)
          v[u] = *(const uint2*)(base + (size_t)(blk + u) * 4096);
#pragma unroll
        for (int u = 0; u < 16; u++) {
          int j = jb + blk + u;
          if (v[u].x & 0xffffu) { if (p0 < SLOTS) c0[p0] = j;            p0++; }
          if (v[u].x >> 16)     { if (p1 < SLOTS) c0[CAPN + p1] = j;     p1++; }
          if (v[u].y & 0xffffu) { if (p2 < SLOTS) c0[2 * CAPN + p2] = j; p2++; }
          if (v[u].y >> 16)     { if (p3 < SLOTS) c0[3 * CAPN + p3] = j; p3++; }
        }
      }
    } else {
      const float* base = (const float*)adjp + ((size_t)b << 24) +
                          (size_t)jb * 4096 + i0 + 4 * lane;
      for (int blk = 0; blk < 512; blk += 16) {
        float4 v[16];
#pragma unroll
        for (int u = 0; u < 16; u++)
          v[u] = *(const float4*)(base + (size_t)(blk + u) * 4096);
#pragma unroll
        for (int u = 0; u < 16; u++) {
          int j = jb + blk + u;
          if (v[u].x != 0.0f) { if (p0 < SLOTS) c0[p0] = j;            p0++; }
          if (v[u].y != 0.0f) { if (p1 < SLOTS) c0[CAPN + p1] = j;     p1++; }
          if (v[u].z != 0.0f) { if (p2 < SLOTS) c0[2 * CAPN + p2] = j; p2++; }
          if (v[u].w != 0.0f) { if (p3 < SLOTS) c0[3 * CAPN + p3] = j; p3++; }
        }
      }
    }
    size_t sb = (size_t)rb * 8 + s;
    scnt[sb]      = (uint8_t)(p0 > SLOTS ? SLOTS : p0);
    scnt[sb + 8]  = (uint8_t)(p1 > SLOTS ? SLOTS : p1);
    scnt[sb + 16] = (uint8_t)(p2 > SLOTS ? SLOTS : p2);
    scnt[sb + 24] = (uint8_t)(p3 > SLOTS ? SLOTS : p3);
  } else if (bid < 640) {
    // ---- X conversion: grid-stride (512 blocks) ----
    if (flagv) {
      const uint4* in = (const uint4*)xp;
      for (int gid = (bid - 128) * 256 + tid; gid < 1048576; gid += 131072)
        ((uint4*)xb)[gid] = in[gid];
    } else {
      const float4* in = (const float4*)xp;
      for (int gid = (bid - 128) * 256 + tid; gid < 1048576; gid += 131072) {
#pragma unroll
        for (int it = 0; it < 2; it++) {
          int i = gid + it * 1048576;
          float4 v = in[i];
          uint32_t lo = (uint32_t)f2bf(v.x) | ((uint32_t)f2bf(v.y) << 16);
          uint32_t hi = (uint32_t)f2bf(v.z) | ((uint32_t)f2bf(v.w) << 16);
          ((uint2*)xb)[i] = make_uint2(lo, hi);
        }
      }
    }
  } else {
    // ---- W transpose via LDS tile: 192 blocks (verified R8/R9) ----
    int wi = bid - 640;
    int w = wi >> 6;
    int tile = wi & 63;
    int tm = tile >> 3, tn = tile & 7;
    const void* wp = (w == 0) ? w1 : (w == 1) ? w2 : w3;
    ushort* wt = (w == 0) ? wt1 : (w == 1) ? wt2 : wt3;
    int tx = tid & 63, ty = tid >> 6;
    if (flagv) {
      const ushort* ws = (const ushort*)wp;
#pragma unroll
      for (int s = 0; s < 64; s += 4) {
        int row = s + ty;
        lw[row][tx] = ws[(size_t)(tm * 64 + row) * 512 + tn * 64 + tx];
      }
    } else {
      const float* ws = (const float*)wp;
#pragma unroll
      for (int s = 0; s < 64; s += 4) {
        int row = s + ty;
        lw[row][tx] = __float_as_uint(ws[(size_t)(tm * 64 + row) * 512 + tn * 64 + tx]);
      }
    }
    __syncthreads();
#pragma unroll
    for (int s = 0; s < 64; s += 4) {
      int row = s + ty;
      uint32_t bits = lw[tx][row];
      ushort o = flagv ? (ushort)bits : f2bf(__uint_as_float(bits));
      wt[(size_t)(tn * 64 + row) * 512 + tm * 64 + tx] = o;
    }
  }
}

// ---------- bf16 MFMA GEMM: Z[M,512] = X[M,512] @ W  (WT is [n][k]) ----------
__device__ __forceinline__ void gl_lds16(const ushort* g, ushort* l) {
  __builtin_amdgcn_global_load_lds((glb_u32*)g, (lds_u32*)l, 16, 0, 0);
}

__global__ __launch_bounds__(256) void k_gemm(const ushort* __restrict__ X,
                                              const ushort* __restrict__ WT,
                                              ushort* __restrict__ Z) {
  __shared__ ushort As[128 * 32];
  __shared__ ushort Bs[128 * 32];
  const int K = 512, NO = 512;
  int tid = threadIdx.x;
  int m0 = blockIdx.y * 128, n0 = blockIdx.x * 128;
  int lane = tid & 63;
  int wv = tid >> 6;
  int wm = (wv >> 1) << 6;
  int wn = (wv & 1) << 6;
  int lr = lane & 15;
  int lq = lane >> 4;

  f32x4 zero = {0.f, 0.f, 0.f, 0.f};
  f32x4 acc[4][4];
#pragma unroll
  for (int im = 0; im < 4; im++)
#pragma unroll
    for (int in_ = 0; in_ < 4; in_++) acc[im][in_] = zero;

  const ushort* Xg = X  + (size_t)(m0 + (tid >> 2)) * K + ((tid & 3) << 3);
  const ushort* Wg = WT + (size_t)(n0 + (tid >> 2)) * K + ((tid & 3) << 3);

  for (int kt = 0; kt < K; kt += 32) {
    __syncthreads();
    gl_lds16(Xg + kt,                    &As[tid * 8]);
    gl_lds16(Xg + kt + (size_t)64 * K,   &As[2048 + tid * 8]);
    gl_lds16(Wg + kt,                    &Bs[tid * 8]);
    gl_lds16(Wg + kt + (size_t)64 * K,   &Bs[2048 + tid * 8]);
    __syncthreads();
    bf16x8 af[4], bfr[4];
#pragma unroll
    for (int im = 0; im < 4; im++)
      af[im] = *(const bf16x8*)&As[(wm + im * 16 + lr) * 32 + lq * 8];
#pragma unroll
    for (int in_ = 0; in_ < 4; in_++)
      bfr[in_] = *(const bf16x8*)&Bs[(wn + in_ * 16 + lr) * 32 + lq * 8];
#pragma unroll
    for (int im = 0; im < 4; im++)
#pragma unroll
      for (int in_ = 0; in_ < 4; in_++)
        acc[im][in_] = __builtin_amdgcn_mfma_f32_16x16x32_bf16(
            af[im], bfr[in_], acc[im][in_], 0, 0, 0);
  }

#pragma unroll
  for (int im = 0; im < 4; im++) {
    int row0 = m0 + wm + im * 16 + lq * 4;
#pragma unroll
    for (int in_ = 0; in_ < 4; in_++) {
      int col = n0 + wn + in_ * 16 + lr;
#pragma unroll
      for (int r = 0; r < 4; r++)
        Z[(size_t)(row0 + r) * NO + col] = f2bf(acc[im][in_][r]);
    }
  }
}

// ---------- SpMM: out[r,:] = sum_j d_r*d_j * Z[j,:] (+bias, relu) ----------
// Segmented CSR consumer — byte-identical to the R9-verified version.
__global__ __launch_bounds__(256) void k_spmm(const ushort* __restrict__ Z,
                                              const uint8_t* __restrict__ scnt,
                                              const int* __restrict__ cols,
                                              const void* __restrict__ bias,
                                              void* __restrict__ outp,
                                              int do_relu, int is_final,
                                              const int* __restrict__ flag) {
  __shared__ int   sj[RPB][CAPN];
  __shared__ float sv[RPB][CAPN];
  int B = blockIdx.x;                 // 4096 blocks
  int wv = threadIdx.x >> 6;
  int lane = threadIdx.x & 63;
  int batch = (B & 7) >> 1;
  int lb = ((B >> 3) << 1) | (B & 1);           // [0,1024)
  int r = (batch << 12) + lb * RPB + wv;
  int base = batch << 12;

  uint64_t s8 = *(const uint64_t*)(scnt + (size_t)r * 8);
  int cr = (int)((s8 * 0x0101010101010101ull) >> 56);
  float dr = (cr > 0) ? 1.0f / sqrtf((float)cr) : 0.0f;
  int run = 0;
#pragma unroll
  for (int s = 0; s < SEGS; s++) {
    int sc = (int)((s8 >> (8 * s)) & 255);      // <= SLOTS < 64
    if (lane < sc) {
      int j = __builtin_nontemporal_load(
          &cols[(size_t)r * CAPN + s * SLOTS + lane]);
      uint64_t t8 = *(const uint64_t*)(scnt + ((size_t)(base + j)) * 8);
      int cj = (int)((t8 * 0x0101010101010101ull) >> 56);
      sj[wv][run + lane] = j;
      sv[wv][run + lane] = dr * ((cj > 0) ? 1.0f / sqrtf((float)cj) : 0.0f);
    }
    run += sc;
  }
  int nnz = run;                                 // <= CAPN

  const ushort* Zb = Z + (size_t)base * 512 + lane * 8;
  float a[8];
  if (flag[0]) {
    uint4 bb = *((const uint4*)bias + lane);    // 8 bf16 at elem lane*8
    uint32_t w[4] = {bb.x, bb.y, bb.z, bb.w};
#pragma unroll
    for (int q = 0; q < 4; q++) {
      a[q * 2]     = bf2f(w[q] & 0xffffu);
      a[q * 2 + 1] = bf2f(w[q] >> 16);
    }
  } else {
    const float4* bp = (const float4*)bias + lane * 2;
    float4 bb0 = bp[0], bb1 = bp[1];
    a[0] = bb0.x; a[1] = bb0.y; a[2] = bb0.z; a[3] = bb0.w;
    a[4] = bb1.x; a[5] = bb1.y; a[6] = bb1.z; a[7] = bb1.w;
  }

  int k = 0;
  for (; k + 2 <= nnz; k += 2) {
    int j0 = sj[wv][k], j1 = sj[wv][k + 1];
    float v0 = sv[wv][k], v1 = sv[wv][k + 1];
    uint4 z0 = *(const uint4*)(Zb + (size_t)j0 * 512);
    uint4 z1 = *(const uint4*)(Zb + (size_t)j1 * 512);
    uint32_t w0[4] = {z0.x, z0.y, z0.z, z0.w};
    uint32_t w1[4] = {z1.x, z1.y, z1.z, z1.w};
#pragma unroll
    for (int q = 0; q < 4; q++) {
      a[q * 2]     += v0 * as_f32(w0[q] << 16);
      a[q * 2 + 1] += v0 * as_f32(w0[q] & 0xffff0000u);
      a[q * 2]     += v1 * as_f32(w1[q] << 16);
      a[q * 2 + 1] += v1 * as_f32(w1[q] & 0xffff0000u);
    }
  }
  if (k < nnz) {
    int j0 = sj[wv][k];
    float v0 = sv[wv][k];
    uint4 z0 = *(const uint4*)(Zb + (size_t)j0 * 512);
    uint32_t w0[4] = {z0.x, z0.y, z0.z, z0.w};
#pragma unroll
    for (int q = 0; q < 4; q++) {
      a[q * 2]     += v0 * as_f32(w0[q] << 16);
      a[q * 2 + 1] += v0 * as_f32(w0[q] & 0xffff0000u);
    }
  }

  if (do_relu) {
#pragma unroll
    for (int q = 0; q < 8; q++) a[q] = fmaxf(a[q], 0.f);
  }

  if (!is_final || flag[0]) {
    u32x4 o;
    o[0] = (uint32_t)f2bf(a[0]) | ((uint32_t)f2bf(a[1]) << 16);
    o[1] = (uint32_t)f2bf(a[2]) | ((uint32_t)f2bf(a[3]) << 16);
    o[2] = (uint32_t)f2bf(a[4]) | ((uint32_t)f2bf(a[5]) << 16);
    o[3] = (uint32_t)f2bf(a[6]) | ((uint32_t)f2bf(a[7]) << 16);
    __builtin_nontemporal_store(
        o, (u32x4*)((ushort*)outp + (size_t)r * 512 + lane * 8));
  } else {
    f32x4 o0 = {a[0], a[1], a[2], a[3]};
    f32x4 o1 = {a[4], a[5], a[6], a[7]};
    f32x4* op = (f32x4*)((float*)outp + (size_t)r * 512 + lane * 8);
    __builtin_nontemporal_store(o0, op);
    __builtin_nontemporal_store(o1, op + 1);
  }
}

extern "C" void kernel_launch(void* const* d_in, const int* in_sizes, int n_in,
                              void* d_out, int out_size, void* d_ws, size_t ws_size,
                              hipStream_t stream) {
  const void* X  = d_in[0];
  const void* A  = d_in[1];
  const void* W1 = d_in[2]; const void* b1 = d_in[3];
  const void* W2 = d_in[4]; const void* b2 = d_in[5];
  const void* W3 = d_in[6]; const void* b3 = d_in[7];

  char* ws = (char*)d_ws;
  size_t off = 0;
  auto alloc = [&](size_t bytes) -> void* {
    void* p = ws + off;
    off += (bytes + 255) & ~(size_t)255;
    return p;
  };
  uint8_t* scnt = (uint8_t*)alloc(16384 * 8);
  int*     flag = (int*)alloc(4);
  int*     cols = (int*)alloc((size_t)16384 * CAPN * 4);
  ushort*  W1T  = (ushort*)alloc(512 * 512 * 2);
  ushort*  W2T  = (ushort*)alloc(512 * 512 * 2);
  ushort*  W3T  = (ushort*)alloc(512 * 512 * 2);
  ushort*  Xb   = (ushort*)alloc((size_t)16384 * 512 * 2);
  ushort*  Zb   = (ushort*)alloc((size_t)16384 * 512 * 2);
  ushort*  Hb   = (ushort*)alloc((size_t)16384 * 512 * 2);

  // 8 dispatches.
  k_init<<<1, 256, 0, stream>>>((const uint32_t*)A, flag);
  k_stage<<<832, 256, 0, stream>>>(A, scnt, cols, X, Xb,
                                   W1, W2, W3, W1T, W2T, W3T, flag);

  dim3 gg(4, 128);
  k_gemm<<<gg, 256, 0, stream>>>(Xb, W1T, Zb);
  k_spmm<<<4096, 256, 0, stream>>>(Zb, scnt, cols, b1, Hb, 1, 0, flag);
  k_gemm<<<gg, 256, 0, stream>>>(Hb, W2T, Zb);
  k_spmm<<<4096, 256, 0, stream>>>(Zb, scnt, cols, b2, Xb, 1, 0, flag);
  k_gemm<<<gg, 256, 0, stream>>>(Xb, W3T, Zb);
  k_spmm<<<4096, 256, 0, stream>>>(Zb, scnt, cols, b3, d_out, 0, 1, flag);
}

// Round 11
// 590.534 us; speedup vs baseline: 1.1534x; 1.1534x over previous
//
#include <hip/hip_runtime.h>
#include <stdint.h>

#define CAP 128   // max nnz per normalized-adj row (Poisson(41): P(>=128) ~ 1e-26)
#define RPB 4     // rows per block in spmm (1 wave each)

typedef __attribute__((ext_vector_type(8))) short bf16x8;
typedef __attribute__((ext_vector_type(4))) float f32x4;

typedef __attribute__((address_space(3))) uint32_t lds_u32;
typedef __attribute__((address_space(1))) const uint32_t glb_u32;

__device__ __forceinline__ unsigned short f2bf(float f) {
  union { float f; uint32_t u; } c; c.f = f;
  return (unsigned short)((c.u + 0x7fffu + ((c.u >> 16) & 1u)) >> 16);
}
__device__ __forceinline__ float bf2f(uint32_t b) {
  union { uint32_t u; float f; } c; c.u = b << 16; return c.f;
}
__device__ __forceinline__ float as_f32(uint32_t u) {
  union { uint32_t u; float f; } c; c.u = u; return c.f;
}

// ---------- init: zero cnt + dtype-detect + write flag (1 block) ----------
// f32 adjacency words are only 0x00000000 / 0x3F800000. bf16-pair words
// (1.0,0.0)=0x00003F80 and (1.0,1.0)=0x3F803F80 cannot occur in f32 data.
__global__ __launch_bounds__(256) void k_init(const uint32_t* __restrict__ a,
                                              int* __restrict__ cnt,
                                              int* __restrict__ flag) {
  __shared__ int sfound;
  int t = threadIdx.x;
  if (t == 0) sfound = 0;
  bool found = false;
  for (int i = t; i < 16384; i += 256) {
    cnt[i] = 0;
    uint32_t x = a[i];
    if (x == 0x00003F80u || x == 0x3F803F80u) found = true;
  }
  __syncthreads();
  if (found) sfound = 1;   // benign same-value race
  __syncthreads();
  if (t == 0) flag[0] = sfound;
}

// ---------- merged CSR build + X conversion + weight transpose ----------
// Build keeps max-TLP tiny-block atomic scatter: measured A/B/C/D across
// R3-R10 shows 683K scattered RMW+store chains are cheapest at 131K waves
// (109us); persistent blocks (R8) = same; atomic-free compaction (R9/R10)
// = +75-80us. Do not redesign without new counter evidence.
__global__ __launch_bounds__(256) void k_stage(const void* __restrict__ adjp,
                                               int* __restrict__ cnt,
                                               int* __restrict__ cols,
                                               const void* __restrict__ xp,
                                               ushort* __restrict__ xb,
                                               const void* w1, const void* w2,
                                               const void* w3,
                                               ushort* __restrict__ wt1,
                                               ushort* __restrict__ wt2,
                                               ushort* __restrict__ wt3,
                                               const int* __restrict__ flag) {
  int bid = blockIdx.x;
  int tid = threadIdx.x;
  if (bid < 32768) {
    // ---- CSR build (32768 blocks -> 8388608 threads) ----
    int gid = bid * 256 + tid;
    if (flag[0]) {
      const uint4* a = (const uint4*)adjp;
      uint4 v = a[gid];
      int i0 = (gid & 511) * 8;
      int j  = (gid >> 9) & 4095;
      int b  = gid >> 21;
      int base = b << 12;
      uint32_t w[4] = {v.x, v.y, v.z, v.w};
#pragma unroll
      for (int q = 0; q < 4; q++) {
        if (w[q] & 0xffffu) {
          int c = base + i0 + q * 2;
          int p = atomicAdd(&cnt[c], 1);
          if (p < CAP) cols[(size_t)c * CAP + p] = j;
        }
        if (w[q] >> 16) {
          int c = base + i0 + q * 2 + 1;
          int p = atomicAdd(&cnt[c], 1);
          if (p < CAP) cols[(size_t)c * CAP + p] = j;
        }
      }
    } else {
      const float4* a = (const float4*)adjp;
#pragma unroll
      for (int it = 0; it < 2; it++) {
        int v4 = gid + it * 8388608;
        float4 v = a[v4];
        int i0 = (v4 & 1023) * 4;
        int j  = (v4 >> 10) & 4095;
        int b  = v4 >> 22;
        int base = b << 12;
        float e[4] = {v.x, v.y, v.z, v.w};
#pragma unroll
        for (int q = 0; q < 4; q++) {
          if (e[q] != 0.0f) {
            int c = base + i0 + q;
            int p = atomicAdd(&cnt[c], 1);
            if (p < CAP) cols[(size_t)c * CAP + p] = j;
          }
        }
      }
    }
  } else if (bid < 36864) {
    // ---- X conversion (4096 blocks -> 1048576 threads) ----
    int gid = (bid - 32768) * 256 + tid;
    if (flag[0]) {
      const uint4* in = (const uint4*)xp;
      ((uint4*)xb)[gid] = in[gid];
    } else {
      const float4* in = (const float4*)xp;
#pragma unroll
      for (int it = 0; it < 2; it++) {
        int i = gid + it * 1048576;
        float4 v = in[i];
        uint32_t lo = (uint32_t)f2bf(v.x) | ((uint32_t)f2bf(v.y) << 16);
        uint32_t hi = (uint32_t)f2bf(v.z) | ((uint32_t)f2bf(v.w) << 16);
        ((uint2*)xb)[i] = make_uint2(lo, hi);
      }
    }
  } else {
    // ---- weight transpose+convert (3072 blocks -> 786432 threads) ----
    int id = (bid - 36864) * 256 + tid;
    int w = id >> 18;                          // 262144 elems each
    int o = id & 262143;
    const void* wp = (w == 0) ? w1 : (w == 1) ? w2 : w3;
    ushort* wt = (w == 0) ? wt1 : (w == 1) ? wt2 : wt3;
    int n = o >> 9, k = o & 511;
    if (flag[0]) wt[o] = ((const ushort*)wp)[k * 512 + n];
    else         wt[o] = f2bf(((const float*)wp)[k * 512 + n]);
  }
}

// ---------- bf16 MFMA GEMM: Z[M,512] = X[M,512] @ W  (WT is [n][k]) ----------
__device__ __forceinline__ void gl_lds16(const ushort* g, ushort* l) {
  __builtin_amdgcn_global_load_lds((glb_u32*)g, (lds_u32*)l, 16, 0, 0);
}

__global__ __launch_bounds__(256) void k_gemm(const ushort* __restrict__ X,
                                              const ushort* __restrict__ WT,
                                              ushort* __restrict__ Z) {
  __shared__ ushort As[128 * 32];
  __shared__ ushort Bs[128 * 32];
  const int K = 512, NO = 512;
  int tid = threadIdx.x;
  int m0 = blockIdx.y * 128, n0 = blockIdx.x * 128;
  int lane = tid & 63;
  int wv = tid >> 6;
  int wm = (wv >> 1) << 6;
  int wn = (wv & 1) << 6;
  int lr = lane & 15;
  int lq = lane >> 4;

  f32x4 zero = {0.f, 0.f, 0.f, 0.f};
  f32x4 acc[4][4];
#pragma unroll
  for (int im = 0; im < 4; im++)
#pragma unroll
    for (int in_ = 0; in_ < 4; in_++) acc[im][in_] = zero;

  const ushort* Xg = X  + (size_t)(m0 + (tid >> 2)) * K + ((tid & 3) << 3);
  const ushort* Wg = WT + (size_t)(n0 + (tid >> 2)) * K + ((tid & 3) << 3);

  for (int kt = 0; kt < K; kt += 32) {
    __syncthreads();
    gl_lds16(Xg + kt,                    &As[tid * 8]);
    gl_lds16(Xg + kt + (size_t)64 * K,   &As[2048 + tid * 8]);
    gl_lds16(Wg + kt,                    &Bs[tid * 8]);
    gl_lds16(Wg + kt + (size_t)64 * K,   &Bs[2048 + tid * 8]);
    __syncthreads();
    bf16x8 af[4], bfr[4];
#pragma unroll
    for (int im = 0; im < 4; im++)
      af[im] = *(const bf16x8*)&As[(wm + im * 16 + lr) * 32 + lq * 8];
#pragma unroll
    for (int in_ = 0; in_ < 4; in_++)
      bfr[in_] = *(const bf16x8*)&Bs[(wn + in_ * 16 + lr) * 32 + lq * 8];
#pragma unroll
    for (int im = 0; im < 4; im++)
#pragma unroll
      for (int in_ = 0; in_ < 4; in_++)
        acc[im][in_] = __builtin_amdgcn_mfma_f32_16x16x32_bf16(
            af[im], bfr[in_], acc[im][in_], 0, 0, 0);
  }

#pragma unroll
  for (int im = 0; im < 4; im++) {
    int row0 = m0 + wm + im * 16 + lq * 4;
#pragma unroll
    for (int in_ = 0; in_ < 4; in_++) {
      int col = n0 + wn + in_ * 16 + lr;
#pragma unroll
      for (int r = 0; r < 4; r++)
        Z[(size_t)(row0 + r) * NO + col] = f2bf(acc[im][in_][r]);
    }
  }
}

// ---------- SpMM: out[r,:] = sum_j d_r*d_j * Z[j,:] (+bias, relu) ----------
// dinv computed on the fly from cnt (self-loops guarantee cnt>=1); bias
// converted inline.
__global__ __launch_bounds__(256) void k_spmm(const ushort* __restrict__ Z,
                                              const int* __restrict__ cnt,
                                              const int* __restrict__ cols,
                                              const void* __restrict__ bias,
                                              void* __restrict__ outp,
                                              int do_relu, int is_final,
                                              const int* __restrict__ flag) {
  __shared__ int   sj[RPB][CAP];
  __shared__ float sv[RPB][CAP];
  int B = blockIdx.x;                 // 4096 blocks
  int wv = threadIdx.x >> 6;
  int lane = threadIdx.x & 63;
  int batch = (B & 7) >> 1;
  int lb = ((B >> 3) << 1) | (B & 1);           // [0,1024)
  int r = (batch << 12) + lb * RPB + wv;
  int base = batch << 12;

  int cr = cnt[r];
  float dr = (cr > 0) ? 1.0f / sqrtf((float)cr) : 0.0f;
  int nnz = (cr > CAP) ? CAP : cr;
  for (int k = lane; k < nnz; k += 64) {        // <=2 iterations (CAP=128)
    int j = cols[(size_t)r * CAP + k];
    int cj = cnt[base + j];
    sj[wv][k] = j;
    sv[wv][k] = dr * ((cj > 0) ? 1.0f / sqrtf((float)cj) : 0.0f);
  }
  // wave-local LDS producer/consumer: lgkmcnt ordering within the wave

  const ushort* Zb = Z + (size_t)base * 512 + lane * 8;
  float a[8];
  if (flag[0]) {
    uint4 bb = *((const uint4*)bias + lane);    // 8 bf16 at elem lane*8
    uint32_t w[4] = {bb.x, bb.y, bb.z, bb.w};
#pragma unroll
    for (int q = 0; q < 4; q++) {
      a[q * 2]     = bf2f(w[q] & 0xffffu);
      a[q * 2 + 1] = bf2f(w[q] >> 16);
    }
  } else {
    const float4* bp = (const float4*)bias + lane * 2;
    float4 bb0 = bp[0], bb1 = bp[1];
    a[0] = bb0.x; a[1] = bb0.y; a[2] = bb0.z; a[3] = bb0.w;
    a[4] = bb1.x; a[5] = bb1.y; a[6] = bb1.z; a[7] = bb1.w;
  }

  int k = 0;
  for (; k + 2 <= nnz; k += 2) {
    int j0 = sj[wv][k], j1 = sj[wv][k + 1];
    float v0 = sv[wv][k], v1 = sv[wv][k + 1];
    uint4 z0 = *(const uint4*)(Zb + (size_t)j0 * 512);
    uint4 z1 = *(const uint4*)(Zb + (size_t)j1 * 512);
    uint32_t w0[4] = {z0.x, z0.y, z0.z, z0.w};
    uint32_t w1[4] = {z1.x, z1.y, z1.z, z1.w};
#pragma unroll
    for (int q = 0; q < 4; q++) {
      a[q * 2]     += v0 * as_f32(w0[q] << 16);
      a[q * 2 + 1] += v0 * as_f32(w0[q] & 0xffff0000u);
      a[q * 2]     += v1 * as_f32(w1[q] << 16);
      a[q * 2 + 1] += v1 * as_f32(w1[q] & 0xffff0000u);
    }
  }
  if (k < nnz) {
    int j0 = sj[wv][k];
    float v0 = sv[wv][k];
    uint4 z0 = *(const uint4*)(Zb + (size_t)j0 * 512);
    uint32_t w0[4] = {z0.x, z0.y, z0.z, z0.w};
#pragma unroll
    for (int q = 0; q < 4; q++) {
      a[q * 2]     += v0 * as_f32(w0[q] << 16);
      a[q * 2 + 1] += v0 * as_f32(w0[q] & 0xffff0000u);
    }
  }

  if (do_relu) {
#pragma unroll
    for (int q = 0; q < 8; q++) a[q] = fmaxf(a[q], 0.f);
  }

  if (!is_final || flag[0]) {
    uint4 o;
    o.x = (uint32_t)f2bf(a[0]) | ((uint32_t)f2bf(a[1]) << 16);
    o.y = (uint32_t)f2bf(a[2]) | ((uint32_t)f2bf(a[3]) << 16);
    o.z = (uint32_t)f2bf(a[4]) | ((uint32_t)f2bf(a[5]) << 16);
    o.w = (uint32_t)f2bf(a[6]) | ((uint32_t)f2bf(a[7]) << 16);
    *(uint4*)((ushort*)outp + (size_t)r * 512 + lane * 8) = o;
  } else {
    float4 o0 = make_float4(a[0], a[1], a[2], a[3]);
    float4 o1 = make_float4(a[4], a[5], a[6], a[7]);
    float4* op = (float4*)((float*)outp + (size_t)r * 512 + lane * 8);
    op[0] = o0; op[1] = o1;
  }
}

extern "C" void kernel_launch(void* const* d_in, const int* in_sizes, int n_in,
                              void* d_out, int out_size, void* d_ws, size_t ws_size,
                              hipStream_t stream) {
  const void* X  = d_in[0];
  const void* A  = d_in[1];
  const void* W1 = d_in[2]; const void* b1 = d_in[3];
  const void* W2 = d_in[4]; const void* b2 = d_in[5];
  const void* W3 = d_in[6]; const void* b3 = d_in[7];

  char* ws = (char*)d_ws;
  size_t off = 0;
  auto alloc = [&](size_t bytes) -> void* {
    void* p = ws + off;
    off += (bytes + 255) & ~(size_t)255;
    return p;
  };
  int*    cnt  = (int*)alloc(16384 * 4);
  int*    flag = (int*)alloc(4);
  int*    cols = (int*)alloc((size_t)16384 * CAP * 4);
  ushort* W1T  = (ushort*)alloc(512 * 512 * 2);
  ushort* W2T  = (ushort*)alloc(512 * 512 * 2);
  ushort* W3T  = (ushort*)alloc(512 * 512 * 2);
  ushort* Xb   = (ushort*)alloc((size_t)16384 * 512 * 2);
  ushort* Zb   = (ushort*)alloc((size_t)16384 * 512 * 2);
  ushort* Hb   = (ushort*)alloc((size_t)16384 * 512 * 2);

  // 8 dispatches total: no memset, detect/prep folded away,
  // build+convx+wconv merged. (Session-best configuration, R3: 591.4us.)
  k_init<<<1, 256, 0, stream>>>((const uint32_t*)A, cnt, flag);
  k_stage<<<39936, 256, 0, stream>>>(A, cnt, cols, X, Xb,
                                     W1, W2, W3, W1T, W2T, W3T, flag);

  dim3 gg(4, 128);
  k_gemm<<<gg, 256, 0, stream>>>(Xb, W1T, Zb);
  k_spmm<<<4096, 256, 0, stream>>>(Zb, cnt, cols, b1, Hb, 1, 0, flag);
  k_gemm<<<gg, 256, 0, stream>>>(Hb, W2T, Zb);
  k_spmm<<<4096, 256, 0, stream>>>(Zb, cnt, cols, b2, Xb, 1, 0, flag);
  k_gemm<<<gg, 256, 0, stream>>>(Xb, W3T, Zb);
  k_spmm<<<4096, 256, 0, stream>>>(Zb, cnt, cols, b3, d_out, 0, 1, flag);
}